// Round 1
// baseline (1235.634 us; speedup 1.0000x reference)
//
#include <hip/hip_runtime.h>
#include <hip/hip_bf16.h>

// ReLU-LSTM fused: 4-gate bf16 MFMA GEMM (A shared across gates) + in-register
// LSTM epilogue. M=4096 (batch), N=2048 (hidden), K=4096 (x|h concat).

#define BM 128
#define BN 64      // per gate
#define BK 64
#define THREADS 256
#define HID 2048
#define BATCH_N 4096

typedef __attribute__((ext_vector_type(4))) float f32x4;
typedef __attribute__((ext_vector_type(8))) short bf16x8;

struct Params {
    const float* x;
    const float* h;
    const float* c;
    const float* Wx[4];   // gate order: f, i, c~, o
    const float* Wh[4];
    const float* bx[4];
    float* oh;            // h_new
    float* oc;            // c_new
};

__device__ __forceinline__ short f2bf(float f) {
    // round-to-nearest-even bf16 (inputs finite; NaN not handled)
    union { float f; unsigned u; } v; v.f = f;
    unsigned r = v.u + 0x7FFFu + ((v.u >> 16) & 1u);
    return (short)(r >> 16);
}

__device__ __forceinline__ float fast_tanh(float v) {
    // tanh(v) = 1 - 2/(exp(2v)+1); saturates correctly at +-inf of __expf
    float e = __expf(2.0f * v);
    return 1.0f - 2.0f / (e + 1.0f);
}

__global__ __launch_bounds__(THREADS, 2) void relulstm_kernel(Params p) {
    // LDS: [row][k] bf16, XOR-swizzled in 8-elem units: idx = row*BK + (k ^ ((row&7)<<3))
    __shared__ short sA[BM * BK];          // 16 KB
    __shared__ short sB[4][BN * BK];       // 32 KB

    const int t = threadIdx.x;
    const int bm = blockIdx.x * BM;        // batch-tile
    const int bn = blockIdx.y * BN;        // hidden-tile

    const int wave = t >> 6;
    const int lane = t & 63;
    const int wm = (wave >> 1) * 64;       // wave row offset within tile
    const int wn = (wave & 1) * 32;        // wave col offset within tile
    const int lr = lane & 15;              // A-row / B-col within fragment
    const int lk = (lane >> 4) * 8;        // k offset within fragment

    f32x4 acc[4][4][2];                    // [gate][m-frag][n-frag]
    #pragma unroll
    for (int g = 0; g < 4; ++g)
        #pragma unroll
        for (int m = 0; m < 4; ++m)
            #pragma unroll
            for (int n = 0; n < 2; ++n)
                acc[g][m][n] = (f32x4){0.f, 0.f, 0.f, 0.f};

    for (int k0 = 0; k0 < 2 * HID; k0 += BK) {
        const bool xpart = (k0 < HID);
        const int kb = k0 & (HID - 1);

        // ---- stage A: 128 rows x 64 k, 4-float chunks, 8 per thread ----
        const float* __restrict__ srcA = xpart ? p.x : p.h;
        #pragma unroll
        for (int i2 = 0; i2 < 8; ++i2) {
            int cidx = t + i2 * THREADS;       // 0..2047
            int row = cidx >> 4;
            int kc = cidx & 15;
            float4 v = *(const float4*)&srcA[(size_t)(bm + row) * HID + kb + kc * 4];
            int idx = row * BK + ((kc * 4) ^ ((row & 7) << 3));
            short4 s;
            s.x = f2bf(v.x); s.y = f2bf(v.y); s.z = f2bf(v.z); s.w = f2bf(v.w);
            *(short4*)&sA[idx] = s;
        }

        // ---- stage B: 4 gates x 64 rows x 64 k, 16 chunks per thread ----
        #pragma unroll
        for (int i2 = 0; i2 < 16; ++i2) {
            const int g = i2 >> 2;             // compile-time per unrolled i2
            int rem = t + (i2 & 3) * THREADS;  // 0..1023
            int row = rem >> 4;
            int kc = rem & 15;
            const float* __restrict__ srcB = xpart ? p.Wx[g] : p.Wh[g];
            float4 v = *(const float4*)&srcB[(size_t)(bn + row) * HID + kb + kc * 4];
            int idx = row * BK + ((kc * 4) ^ ((row & 7) << 3));
            short4 s;
            s.x = f2bf(v.x); s.y = f2bf(v.y); s.z = f2bf(v.z); s.w = f2bf(v.w);
            *(short4*)&sB[g][idx] = s;
        }

        __syncthreads();

        // ---- MFMA: per wave 64x32 per gate; A-frags reused across 4 gates ----
        #pragma unroll
        for (int kk = 0; kk < 2; ++kk) {
            bf16x8 a[4];
            #pragma unroll
            for (int m = 0; m < 4; ++m) {
                int row = wm + m * 16 + lr;
                int kidx = (kk * 32 + lk) ^ ((row & 7) << 3);
                a[m] = *(const bf16x8*)&sA[row * BK + kidx];
            }
            #pragma unroll
            for (int g = 0; g < 4; ++g) {
                #pragma unroll
                for (int n = 0; n < 2; ++n) {
                    int brow = wn + n * 16 + lr;
                    int kidx = (kk * 32 + lk) ^ ((brow & 7) << 3);
                    bf16x8 b = *(const bf16x8*)&sB[g][brow * BK + kidx];
                    #pragma unroll
                    for (int m = 0; m < 4; ++m)
                        acc[g][m][n] = __builtin_amdgcn_mfma_f32_16x16x32_bf16(
                            a[m], b, acc[g][m][n], 0, 0, 0);
                }
            }
        }

        __syncthreads();
    }

    // ---- epilogue: bias + ReLU/tanh + LSTM cell update, all in-register ----
    // C/D layout (16x16): col = lane&15, row = (lane>>4)*4 + reg   [m89-verified]
    float bias[4][2];
    #pragma unroll
    for (int g = 0; g < 4; ++g)
        #pragma unroll
        for (int n = 0; n < 2; ++n)
            bias[g][n] = p.bx[g][bn + wn + n * 16 + lr];

    #pragma unroll
    for (int m = 0; m < 4; ++m) {
        int rbase = bm + wm + m * 16 + (lane >> 4) * 4;
        #pragma unroll
        for (int r = 0; r < 4; ++r) {
            int row = rbase + r;
            #pragma unroll
            for (int n = 0; n < 2; ++n) {
                int col = bn + wn + n * 16 + lr;
                float pf = acc[0][m][n][r] + bias[0][n];
                float pi = acc[1][m][n][r] + bias[1][n];
                float pc = acc[2][m][n][r] + bias[2][n];
                float po = acc[3][m][n][r] + bias[3][n];
                float fg = fmaxf(pf, 0.f);
                float ig = fmaxf(pi, 0.f);
                float og = fmaxf(po, 0.f);
                float ct = fast_tanh(pc);
                float cv = p.c[(size_t)row * HID + col];
                float cn = fg * cv + ig * ct;
                float hn = og * fast_tanh(cn);
                p.oh[(size_t)row * HID + col] = hn;
                p.oc[(size_t)row * HID + col] = cn;
            }
        }
    }
}

extern "C" void kernel_launch(void* const* d_in, const int* in_sizes, int n_in,
                              void* d_out, int out_size, void* d_ws, size_t ws_size,
                              hipStream_t stream) {
    (void)in_sizes; (void)n_in; (void)out_size; (void)d_ws; (void)ws_size;
    Params p;
    p.x = (const float*)d_in[0];
    p.h = (const float*)d_in[1];
    p.c = (const float*)d_in[2];
    // dict order: Wfx,bfx,Wfh, Wix,bix,Wih, Wcx,bcx,Wch, Wox,box,Woh
    for (int g = 0; g < 4; ++g) {
        p.Wx[g] = (const float*)d_in[3 + 3 * g];
        p.bx[g] = (const float*)d_in[4 + 3 * g];
        p.Wh[g] = (const float*)d_in[5 + 3 * g];
    }
    p.oh = (float*)d_out;
    p.oc = (float*)d_out + (size_t)BATCH_N * HID;

    dim3 grid(BATCH_N / BM, HID / BN);   // 32 x 32
    relulstm_kernel<<<grid, THREADS, 0, stream>>>(p);
}

// Round 2
// 318.442 us; speedup vs baseline: 3.8802x; 3.8802x over previous
//
#include <hip/hip_runtime.h>
#include <hip/hip_bf16.h>

// ReLU-LSTM fused, round 2: precast f32->bf16 (pre-swizzled) into d_ws, then
// m97-style global_load_lds GEMM with 4-gate shared-A accumulation and
// in-register LSTM epilogue.

#define HID 2048
#define BATCH_N 4096
#define KTOT 4096          // K = 2*HID ([x|h] concat)
#define BM 128
#define BN 64              // per gate
#define BK 64
#define THREADS 256

typedef __attribute__((ext_vector_type(4))) float f32x4;
typedef __attribute__((ext_vector_type(8))) short bf16x8;

__device__ __forceinline__ short f2bf(float f) {
    union { float f; unsigned u; } v; v.f = f;
    unsigned r = v.u + 0x7FFFu + ((v.u >> 16) & 1u);
    return (short)(r >> 16);
}

__device__ __forceinline__ float fast_tanh(float v) {
    float e = __expf(2.0f * v);
    return 1.0f - 2.0f / (e + 1.0f);
}

__device__ __forceinline__ void gload_lds16(const short* g, short* l) {
    __builtin_amdgcn_global_load_lds(
        (const __attribute__((address_space(1))) unsigned int*)g,
        (__attribute__((address_space(3))) unsigned int*)l, 16, 0, 0);
}

// ---------------------------------------------------------------------------
// Kernel 1: precast f32 -> bf16 with within-64 K-swizzle keyed on (row&7).
// A[row][col] row in [0,4096) over [x|h]; B[g][row][col] weights [Wx|Wh].
// Stored col = (k & ~63) | ((k&63) ^ ((row&7)<<3)) so that a LINEAR
// global_load_lds stage yields a swizzled LDS tile (rule 21).
// ---------------------------------------------------------------------------
struct CastParams {
    const float* x; const float* h;
    const float* Wx[4]; const float* Wh[4];
    short* A; short* B;
};

__global__ __launch_bounds__(256) void precast_kernel(CastParams q) {
    const long A_CH = (long)BATCH_N * (KTOT / 8);   // 2^21 16B-chunks
    const long B_CH = 4L * HID * (KTOT / 8);        // 2^22
    const long total = A_CH + B_CH;
    for (long idx = (long)blockIdx.x * 256 + threadIdx.x; idx < total;
         idx += (long)gridDim.x * 256) {
        const float* src; short* dst; int row, k;
        if (idx < A_CH) {
            row = (int)(idx >> 9);
            k = (int)(idx & 511) << 3;
            src = (k < HID) ? &q.x[(size_t)row * HID + k]
                            : &q.h[(size_t)row * HID + (k - HID)];
            dst = &q.A[(size_t)row * KTOT];
        } else {
            long r = idx - A_CH;
            int g = (int)(r >> 20);                 // 2048*512 = 2^20 per gate
            int rem = (int)(r & ((1 << 20) - 1));
            row = rem >> 9;
            k = (rem & 511) << 3;
            src = (k < HID) ? &q.Wx[g][(size_t)row * HID + k]
                            : &q.Wh[g][(size_t)row * HID + (k - HID)];
            dst = &q.B[((size_t)g * HID + row) * KTOT];
        }
        float4 v0 = *(const float4*)src;
        float4 v1 = *(const float4*)(src + 4);
        int col = (k & ~63) | ((k & 63) ^ ((row & 7) << 3));
        bf16x8 s;
        s[0] = f2bf(v0.x); s[1] = f2bf(v0.y); s[2] = f2bf(v0.z); s[3] = f2bf(v0.w);
        s[4] = f2bf(v1.x); s[5] = f2bf(v1.y); s[6] = f2bf(v1.z); s[7] = f2bf(v1.w);
        *(bf16x8*)&dst[col] = s;
    }
}

// ---------------------------------------------------------------------------
// Kernel 2: fused 4-gate GEMM + LSTM epilogue, m97 structure.
// Block: 128 (batch) x 64 (hidden) x all 4 gates. 4 waves, 2x2.
// Staging: global_load_lds width 16, linear LDS dest; ds_read applies swizzle.
// ---------------------------------------------------------------------------
struct GemmParams {
    const short* A; const short* B;
    const float* bx[4];
    const float* c;
    float* oh; float* oc;
};

__global__ __launch_bounds__(THREADS, 2) void gemm_lstm_kernel(GemmParams p) {
    __shared__ short sA[BM * BK];        // 16 KB
    __shared__ short sB[4 * BN * BK];    // 32 KB

    const int t = threadIdx.x;
    const int bm = blockIdx.x * BM;
    const int bn = blockIdx.y * BN;
    const int wave = t >> 6;
    const int lane = t & 63;
    const int wm = (wave >> 1) * 64;
    const int wn = (wave & 1) * 32;
    const int lr = lane & 15;
    const int lk = (lane >> 4) * 8;

    f32x4 acc[4][4][2];
    #pragma unroll
    for (int g = 0; g < 4; ++g)
        #pragma unroll
        for (int m = 0; m < 4; ++m)
            #pragma unroll
            for (int n = 0; n < 2; ++n)
                acc[g][m][n] = (f32x4){0.f, 0.f, 0.f, 0.f};

    // staging geometry: per global_load_lds call a wave covers 8 rows x 64 k
    const int srow = lane >> 3;              // row within 8-row group
    const int kch = (lane & 7) * 8;          // k-chunk (elements)
    const short* gA = p.A + (size_t)(bm + wave * 32 + srow) * KTOT + kch;
    // B: wave w stages gate w; n = j*8 + srow
    const short* gB = p.B + ((size_t)wave * HID + bn + srow) * KTOT + kch;

    for (int k0 = 0; k0 < KTOT; k0 += BK) {
        #pragma unroll
        for (int j = 0; j < 4; ++j)
            gload_lds16(gA + (size_t)(j * 8) * KTOT + k0,
                        &sA[(wave * 32 + j * 8) * BK]);
        #pragma unroll
        for (int j = 0; j < 8; ++j)
            gload_lds16(gB + (size_t)(j * 8) * KTOT + k0,
                        &sB[(wave * 64 + j * 8) * BK]);

        __syncthreads();

        #pragma unroll
        for (int kk = 0; kk < 2; ++kk) {
            bf16x8 a[4];
            #pragma unroll
            for (int m = 0; m < 4; ++m) {
                int row = wm + m * 16 + lr;
                int kidx = (kk * 32 + lk) ^ ((row & 7) << 3);
                a[m] = *(const bf16x8*)&sA[row * BK + kidx];
            }
            #pragma unroll
            for (int g = 0; g < 4; ++g) {
                #pragma unroll
                for (int n = 0; n < 2; ++n) {
                    int brow = wn + n * 16 + lr;
                    int kidx = (kk * 32 + lk) ^ ((brow & 7) << 3);
                    bf16x8 b = *(const bf16x8*)&sB[(g * BN + brow) * BK + kidx];
                    #pragma unroll
                    for (int m = 0; m < 4; ++m)
                        acc[g][m][n] = __builtin_amdgcn_mfma_f32_16x16x32_bf16(
                            a[m], b, acc[g][m][n], 0, 0, 0);
                }
            }
        }

        __syncthreads();
    }

    // epilogue: bias + ReLU/tanh + cell update (C/D: col=lane&15, row=(lane>>4)*4+r)
    float bias[4][2];
    #pragma unroll
    for (int g = 0; g < 4; ++g)
        #pragma unroll
        for (int n = 0; n < 2; ++n)
            bias[g][n] = p.bx[g][bn + wn + n * 16 + lr];

    #pragma unroll
    for (int m = 0; m < 4; ++m) {
        int rbase = bm + wm + m * 16 + (lane >> 4) * 4;
        #pragma unroll
        for (int r = 0; r < 4; ++r) {
            int row = rbase + r;
            #pragma unroll
            for (int n = 0; n < 2; ++n) {
                int col = bn + wn + n * 16 + lr;
                float pf = acc[0][m][n][r] + bias[0][n];
                float pi = acc[1][m][n][r] + bias[1][n];
                float pc = acc[2][m][n][r] + bias[2][n];
                float po = acc[3][m][n][r] + bias[3][n];
                float fg = fmaxf(pf, 0.f);
                float ig = fmaxf(pi, 0.f);
                float og = fmaxf(po, 0.f);
                float ct = fast_tanh(pc);
                float cv = p.c[(size_t)row * HID + col];
                float cn = fg * cv + ig * ct;
                float hn = og * fast_tanh(cn);
                p.oh[(size_t)row * HID + col] = hn;
                p.oc[(size_t)row * HID + col] = cn;
            }
        }
    }
}

// ---------------------------------------------------------------------------
// Fallback (round-1 fused kernel, f32 in-loop cast) if d_ws is too small.
// ---------------------------------------------------------------------------
struct Params {
    const float* x; const float* h; const float* c;
    const float* Wx[4]; const float* Wh[4]; const float* bx[4];
    float* oh; float* oc;
};

__global__ __launch_bounds__(THREADS, 2) void relulstm_fallback(Params p) {
    __shared__ short sA[BM * BK];
    __shared__ short sB[4][BN * BK];
    const int t = threadIdx.x;
    const int bm = blockIdx.x * BM;
    const int bn = blockIdx.y * BN;
    const int wave = t >> 6;
    const int lane = t & 63;
    const int wm = (wave >> 1) * 64;
    const int wn = (wave & 1) * 32;
    const int lr = lane & 15;
    const int lk = (lane >> 4) * 8;

    f32x4 acc[4][4][2];
    #pragma unroll
    for (int g = 0; g < 4; ++g)
        #pragma unroll
        for (int m = 0; m < 4; ++m)
            #pragma unroll
            for (int n = 0; n < 2; ++n)
                acc[g][m][n] = (f32x4){0.f, 0.f, 0.f, 0.f};

    for (int k0 = 0; k0 < 2 * HID; k0 += BK) {
        const bool xpart = (k0 < HID);
        const int kb = k0 & (HID - 1);
        const float* __restrict__ srcA = xpart ? p.x : p.h;
        #pragma unroll
        for (int i2 = 0; i2 < 8; ++i2) {
            int cidx = t + i2 * THREADS;
            int row = cidx >> 4;
            int kc = cidx & 15;
            float4 v = *(const float4*)&srcA[(size_t)(bm + row) * HID + kb + kc * 4];
            int idx = row * BK + ((kc * 4) ^ ((row & 7) << 3));
            short4 s;
            s.x = f2bf(v.x); s.y = f2bf(v.y); s.z = f2bf(v.z); s.w = f2bf(v.w);
            *(short4*)&sA[idx] = s;
        }
        #pragma unroll
        for (int i2 = 0; i2 < 16; ++i2) {
            const int g = i2 >> 2;
            int rem = t + (i2 & 3) * THREADS;
            int row = rem >> 4;
            int kc = rem & 15;
            const float* __restrict__ srcB = xpart ? p.Wx[g] : p.Wh[g];
            float4 v = *(const float4*)&srcB[(size_t)(bn + row) * HID + kb + kc * 4];
            int idx = row * BK + ((kc * 4) ^ ((row & 7) << 3));
            short4 s;
            s.x = f2bf(v.x); s.y = f2bf(v.y); s.z = f2bf(v.z); s.w = f2bf(v.w);
            *(short4*)&sB[g][idx] = s;
        }
        __syncthreads();
        #pragma unroll
        for (int kk = 0; kk < 2; ++kk) {
            bf16x8 a[4];
            #pragma unroll
            for (int m = 0; m < 4; ++m) {
                int row = wm + m * 16 + lr;
                int kidx = (kk * 32 + lk) ^ ((row & 7) << 3);
                a[m] = *(const bf16x8*)&sA[row * BK + kidx];
            }
            #pragma unroll
            for (int g = 0; g < 4; ++g) {
                #pragma unroll
                for (int n = 0; n < 2; ++n) {
                    int brow = wn + n * 16 + lr;
                    int kidx = (kk * 32 + lk) ^ ((brow & 7) << 3);
                    bf16x8 b = *(const bf16x8*)&sB[g][brow * BK + kidx];
                    #pragma unroll
                    for (int m = 0; m < 4; ++m)
                        acc[g][m][n] = __builtin_amdgcn_mfma_f32_16x16x32_bf16(
                            a[m], b, acc[g][m][n], 0, 0, 0);
                }
            }
        }
        __syncthreads();
    }

    float bias[4][2];
    #pragma unroll
    for (int g = 0; g < 4; ++g)
        #pragma unroll
        for (int n = 0; n < 2; ++n)
            bias[g][n] = p.bx[g][bn + wn + n * 16 + lr];

    #pragma unroll
    for (int m = 0; m < 4; ++m) {
        int rbase = bm + wm + m * 16 + (lane >> 4) * 4;
        #pragma unroll
        for (int r = 0; r < 4; ++r) {
            int row = rbase + r;
            #pragma unroll
            for (int n = 0; n < 2; ++n) {
                int col = bn + wn + n * 16 + lr;
                float pf = acc[0][m][n][r] + bias[0][n];
                float pi = acc[1][m][n][r] + bias[1][n];
                float pc = acc[2][m][n][r] + bias[2][n];
                float po = acc[3][m][n][r] + bias[3][n];
                float fg = fmaxf(pf, 0.f);
                float ig = fmaxf(pi, 0.f);
                float og = fmaxf(po, 0.f);
                float ct = fast_tanh(pc);
                float cv = p.c[(size_t)row * HID + col];
                float cn = fg * cv + ig * ct;
                float hn = og * fast_tanh(cn);
                p.oh[(size_t)row * HID + col] = hn;
                p.oc[(size_t)row * HID + col] = cn;
            }
        }
    }
}

extern "C" void kernel_launch(void* const* d_in, const int* in_sizes, int n_in,
                              void* d_out, int out_size, void* d_ws, size_t ws_size,
                              hipStream_t stream) {
    (void)in_sizes; (void)n_in; (void)out_size;
    const size_t A_BYTES = (size_t)BATCH_N * KTOT * 2;        // 33.5 MB
    const size_t B_BYTES = (size_t)4 * HID * KTOT * 2;        // 67.1 MB

    if (ws_size >= A_BYTES + B_BYTES) {
        short* A = (short*)d_ws;
        short* B = A + (size_t)BATCH_N * KTOT;

        CastParams q;
        q.x = (const float*)d_in[0];
        q.h = (const float*)d_in[1];
        for (int g = 0; g < 4; ++g) {
            q.Wx[g] = (const float*)d_in[3 + 3 * g];
            q.Wh[g] = (const float*)d_in[5 + 3 * g];
        }
        q.A = A; q.B = B;
        precast_kernel<<<2048, 256, 0, stream>>>(q);

        GemmParams p;
        p.A = A; p.B = B;
        p.c = (const float*)d_in[2];
        for (int g = 0; g < 4; ++g) p.bx[g] = (const float*)d_in[4 + 3 * g];
        p.oh = (float*)d_out;
        p.oc = (float*)d_out + (size_t)BATCH_N * HID;
        dim3 grid(BATCH_N / BM, HID / BN);    // 32 x 32
        gemm_lstm_kernel<<<grid, THREADS, 0, stream>>>(p);
    } else {
        Params p;
        p.x = (const float*)d_in[0];
        p.h = (const float*)d_in[1];
        p.c = (const float*)d_in[2];
        for (int g = 0; g < 4; ++g) {
            p.Wx[g] = (const float*)d_in[3 + 3 * g];
            p.bx[g] = (const float*)d_in[4 + 3 * g];
            p.Wh[g] = (const float*)d_in[5 + 3 * g];
        }
        p.oh = (float*)d_out;
        p.oc = (float*)d_out + (size_t)BATCH_N * HID;
        dim3 grid(BATCH_N / BM, HID / BN);
        relulstm_fallback<<<grid, THREADS, 0, stream>>>(p);
    }
}

// Round 3
// 317.433 us; speedup vs baseline: 3.8926x; 1.0032x over previous
//
#include <hip/hip_runtime.h>
#include <hip/hip_bf16.h>

// ReLU-LSTM fused, round 3: precast f32->bf16 (pre-swizzled) into d_ws, then
// 8-phase counted-vmcnt 256-row GEMM (T2+T3+T4+T5) with 4-gate shared-A
// accumulation and in-register LSTM epilogue.

#define HID 2048
#define BATCH_N 4096
#define KTOT 4096
#define BK 64

typedef __attribute__((ext_vector_type(4))) float f32x4;
typedef __attribute__((ext_vector_type(8))) short bf16x8;

__device__ __forceinline__ short f2bf(float f) {
    union { float f; unsigned u; } v; v.f = f;
    unsigned r = v.u + 0x7FFFu + ((v.u >> 16) & 1u);
    return (short)(r >> 16);
}

__device__ __forceinline__ float fast_tanh(float v) {
    float e = __expf(2.0f * v);
    return 1.0f - 2.0f / (e + 1.0f);
}

__device__ __forceinline__ void gload_lds16(const short* g, short* l) {
    __builtin_amdgcn_global_load_lds(
        (const __attribute__((address_space(1))) unsigned int*)g,
        (__attribute__((address_space(3))) unsigned int*)l, 16, 0, 0);
}

// ---------------------------------------------------------------------------
// Kernel 1: precast f32 -> bf16 with within-64 K-swizzle keyed on (row&7).
// Stored col = (k & ~63) | ((k&63) ^ ((row&7)<<3)) so a LINEAR global_load_lds
// stage yields a swizzled LDS tile (rule 21).
// ---------------------------------------------------------------------------
struct CastParams {
    const float* x; const float* h;
    const float* Wx[4]; const float* Wh[4];
    short* A; short* B;
};

__global__ __launch_bounds__(256) void precast_kernel(CastParams q) {
    const long A_CH = (long)BATCH_N * (KTOT / 8);   // 2^21 16B-chunks
    const long B_CH = 4L * HID * (KTOT / 8);        // 2^22
    const long total = A_CH + B_CH;
    for (long idx = (long)blockIdx.x * 256 + threadIdx.x; idx < total;
         idx += (long)gridDim.x * 256) {
        const float* src; short* dst; int row, k;
        if (idx < A_CH) {
            row = (int)(idx >> 9);
            k = (int)(idx & 511) << 3;
            src = (k < HID) ? &q.x[(size_t)row * HID + k]
                            : &q.h[(size_t)row * HID + (k - HID)];
            dst = &q.A[(size_t)row * KTOT];
        } else {
            long r = idx - A_CH;
            int g = (int)(r >> 20);
            int rem = (int)(r & ((1 << 20) - 1));
            row = rem >> 9;
            k = (rem & 511) << 3;
            src = (k < HID) ? &q.Wx[g][(size_t)row * HID + k]
                            : &q.Wh[g][(size_t)row * HID + (k - HID)];
            dst = &q.B[((size_t)g * HID + row) * KTOT];
        }
        float4 v0 = *(const float4*)src;
        float4 v1 = *(const float4*)(src + 4);
        int col = (k & ~63) | ((k & 63) ^ ((row & 7) << 3));
        bf16x8 s;
        s[0] = f2bf(v0.x); s[1] = f2bf(v0.y); s[2] = f2bf(v0.z); s[3] = f2bf(v0.w);
        s[4] = f2bf(v1.x); s[5] = f2bf(v1.y); s[6] = f2bf(v1.z); s[7] = f2bf(v1.w);
        *(bf16x8*)&dst[col] = s;
    }
}

// ---------------------------------------------------------------------------
// Kernel 2: 8-phase GEMM+LSTM. Block = 256 rows x 64 cols x 4 gates.
// 512 threads = 8 waves (4M x 2N). dbuf0/dbuf1 alternate K-tiles; per
// iteration 2 K-tiles, 8 phases. Stage schedule (region-disjoint, derived):
//   P1: stage dbuf1.Bg2,Bg3(tile 2i+1) | read dbuf0 A+Bg0 | MFMA g0
//   P2: stage dbuf0.A0,A1 (tile 2i+2)  | read Bg1         | MFMA g1
//   P3: stage dbuf0.A2,A3              | read Bg2         | MFMA g2
//   P4: stage dbuf0.Bg0,Bg1            | read Bg3 | vmcnt(6) | MFMA g3
//   P5: stage dbuf0.Bg2,Bg3            | read dbuf1 A+Bg0 | MFMA g0
//   P6: stage dbuf1.A0,A1 (tile 2i+3)  | read Bg1         | MFMA g1
//   P7: stage dbuf1.A2,A3              | read Bg2         | MFMA g2
//   P8: stage dbuf1.Bg0,Bg1            | read Bg3 | vmcnt(6) | MFMA g3
// Every stage target's last read completed >=1 phase earlier (barrier-joined);
// every read's stage landed under the vmcnt(6) guards. Loads never drain to 0.
// ---------------------------------------------------------------------------
struct GemmParams {
    const short* A; const short* B;
    const float* bx[4];
    const float* c;
    float* oh; float* oc;
};

__global__ __launch_bounds__(512, 2) void gemm_lstm_8ph(GemmParams p) {
    __shared__ short sA[2][16384];   // [buf][4 units x 4096]  (256 rows x 64)
    __shared__ short sB[2][16384];   // [buf][4 gates x 4096]  (64 rows x 64)

    const int t = threadIdx.x;
    const int wave = t >> 6;
    const int lane = t & 63;
    const int wr = wave >> 1;            // 0..3 -> rows wr*64
    const int wc = wave & 1;             // 0..1 -> cols wc*32
    const int lr = lane & 15;
    const int lk = (lane >> 4) * 8;
    const int sw = (lane & 7) << 3;      // (row&7)<<3 == (lr&7)<<3 for all frags
    const int koff0 = lk ^ sw;
    const int koff1 = (32 + lk) ^ sw;

    const int bm = blockIdx.x * 256;
    const int bn = blockIdx.y * 64;

    const int aOff = (wr * 64 + lr) * 64;    // + m*1024 + koff
    const int bOff = (wc * 32 + lr) * 64;    // + g*4096 + n*1024 + koff

    const short* aSrc = p.A + (size_t)(bm + (t >> 3)) * KTOT + (t & 7) * 8;
    const short* bSrc = p.B + (size_t)(bn + (t >> 3)) * KTOT + (t & 7) * 8;
    const int ldsT = t * 8;                  // linear dest: t*16B

    f32x4 acc[4][4][2];
    #pragma unroll
    for (int g = 0; g < 4; ++g)
        #pragma unroll
        for (int m = 0; m < 4; ++m)
            #pragma unroll
            for (int n = 0; n < 2; ++n)
                acc[g][m][n] = (f32x4){0.f, 0.f, 0.f, 0.f};

    bf16x8 a[4][2];
    bf16x8 b[2][2];

#define STAGE_A(bf, u, kp) gload_lds16(aSrc + (size_t)(u) * 64 * KTOT + (kp), \
                                       &sA[bf][(u) * 4096 + ldsT])
#define STAGE_B(bf, g, kp) gload_lds16(bSrc + (size_t)(g) * HID * KTOT + (kp), \
                                       &sB[bf][(g) * 4096 + ldsT])
#define READ_A(bf) do { _Pragma("unroll") for (int m = 0; m < 4; ++m) { \
        a[m][0] = *(const bf16x8*)&sA[bf][aOff + m * 1024 + koff0]; \
        a[m][1] = *(const bf16x8*)&sA[bf][aOff + m * 1024 + koff1]; } } while (0)
#define READ_B(bf, g) do { _Pragma("unroll") for (int n = 0; n < 2; ++n) { \
        b[n][0] = *(const bf16x8*)&sB[bf][(g) * 4096 + bOff + n * 1024 + koff0]; \
        b[n][1] = *(const bf16x8*)&sB[bf][(g) * 4096 + bOff + n * 1024 + koff1]; } } while (0)
#define MFMA_G(g) do { __builtin_amdgcn_s_setprio(1); \
        _Pragma("unroll") for (int kk = 0; kk < 2; ++kk) \
        _Pragma("unroll") for (int n = 0; n < 2; ++n) \
        _Pragma("unroll") for (int m = 0; m < 4; ++m) \
            acc[g][m][n] = __builtin_amdgcn_mfma_f32_16x16x32_bf16( \
                a[m][kk], b[n][kk], acc[g][m][n], 0, 0, 0); \
        __builtin_amdgcn_s_setprio(0); } while (0)
#define BAR() __builtin_amdgcn_s_barrier()
#define VMCNT6() asm volatile("s_waitcnt vmcnt(6)" ::: "memory")

    // ---- prologue: tile0 -> dbuf0 (8 units), tile1 -> dbuf1 (A + Bg0,Bg1) ----
    STAGE_A(0, 0, 0); STAGE_A(0, 1, 0); STAGE_A(0, 2, 0); STAGE_A(0, 3, 0);
    STAGE_B(0, 0, 0); STAGE_B(0, 1, 0); STAGE_B(0, 2, 0); STAGE_B(0, 3, 0);
    STAGE_A(1, 0, BK); STAGE_A(1, 1, BK); STAGE_A(1, 2, BK); STAGE_A(1, 3, BK);
    STAGE_B(1, 0, BK); STAGE_B(1, 1, BK);
    VMCNT6();
    BAR();

    for (int it = 0; it < KTOT / (2 * BK); ++it) {
        const int kc1 = ((2 * it + 1) * BK) & (KTOT - 1);
        const int kc2 = ((2 * it + 2) * BK) & (KTOT - 1);  // wraps on last iter (safe)
        const int kc3 = ((2 * it + 3) * BK) & (KTOT - 1);

        // P1
        READ_A(0); READ_B(0, 0);
        STAGE_B(1, 2, kc1); STAGE_B(1, 3, kc1);
        BAR(); MFMA_G(0); BAR();
        // P2
        READ_B(0, 1);
        STAGE_A(0, 0, kc2); STAGE_A(0, 1, kc2);
        BAR(); MFMA_G(1); BAR();
        // P3
        READ_B(0, 2);
        STAGE_A(0, 2, kc2); STAGE_A(0, 3, kc2);
        BAR(); MFMA_G(2); BAR();
        // P4
        READ_B(0, 3);
        STAGE_B(0, 0, kc2); STAGE_B(0, 1, kc2);
        VMCNT6();
        BAR(); MFMA_G(3); BAR();
        // P5
        READ_A(1); READ_B(1, 0);
        STAGE_B(0, 2, kc2); STAGE_B(0, 3, kc2);
        BAR(); MFMA_G(0); BAR();
        // P6
        READ_B(1, 1);
        STAGE_A(1, 0, kc3); STAGE_A(1, 1, kc3);
        BAR(); MFMA_G(1); BAR();
        // P7
        READ_B(1, 2);
        STAGE_A(1, 2, kc3); STAGE_A(1, 3, kc3);
        BAR(); MFMA_G(2); BAR();
        // P8
        READ_B(1, 3);
        STAGE_B(1, 0, kc3); STAGE_B(1, 1, kc3);
        VMCNT6();
        BAR(); MFMA_G(3); BAR();
    }
    asm volatile("s_waitcnt vmcnt(0)" ::: "memory");  // drain before exit

    // ---- epilogue: bias + ReLU/tanh + cell update ----
    // C/D layout (16x16): col = lane&15, row = (lane>>4)*4 + reg
    float bias[4][2];
    #pragma unroll
    for (int g = 0; g < 4; ++g)
        #pragma unroll
        for (int n = 0; n < 2; ++n)
            bias[g][n] = p.bx[g][bn + wc * 32 + n * 16 + lr];

    #pragma unroll
    for (int m = 0; m < 4; ++m) {
        int rbase = bm + wr * 64 + m * 16 + (lane >> 4) * 4;
        #pragma unroll
        for (int r = 0; r < 4; ++r) {
            int row = rbase + r;
            #pragma unroll
            for (int n = 0; n < 2; ++n) {
                int col = bn + wc * 32 + n * 16 + lr;
                float pf = acc[0][m][n][r] + bias[0][n];
                float pi = acc[1][m][n][r] + bias[1][n];
                float pc = acc[2][m][n][r] + bias[2][n];
                float po = acc[3][m][n][r] + bias[3][n];
                float fg = fmaxf(pf, 0.f);
                float ig = fmaxf(pi, 0.f);
                float og = fmaxf(po, 0.f);
                float ct = fast_tanh(pc);
                float cv = p.c[(size_t)row * HID + col];
                float cn = fg * cv + ig * ct;
                float hn = og * fast_tanh(cn);
                p.oh[(size_t)row * HID + col] = hn;
                p.oc[(size_t)row * HID + col] = cn;
            }
        }
    }
#undef STAGE_A
#undef STAGE_B
#undef READ_A
#undef READ_B
#undef MFMA_G
#undef BAR
#undef VMCNT6
}

// ---------------------------------------------------------------------------
// Fallback (round-1 fused kernel) if d_ws is too small.
// ---------------------------------------------------------------------------
struct Params {
    const float* x; const float* h; const float* c;
    const float* Wx[4]; const float* Wh[4]; const float* bx[4];
    float* oh; float* oc;
};

__global__ __launch_bounds__(256, 2) void relulstm_fallback(Params p) {
    __shared__ short sA[128 * 64];
    __shared__ short sB[4][64 * 64];
    const int t = threadIdx.x;
    const int bm = blockIdx.x * 128;
    const int bn = blockIdx.y * 64;
    const int wave = t >> 6;
    const int lane = t & 63;
    const int wm = (wave >> 1) * 64;
    const int wn = (wave & 1) * 32;
    const int lr = lane & 15;
    const int lk = (lane >> 4) * 8;

    f32x4 acc[4][4][2];
    #pragma unroll
    for (int g = 0; g < 4; ++g)
        #pragma unroll
        for (int m = 0; m < 4; ++m)
            #pragma unroll
            for (int n = 0; n < 2; ++n)
                acc[g][m][n] = (f32x4){0.f, 0.f, 0.f, 0.f};

    for (int k0 = 0; k0 < 2 * HID; k0 += BK) {
        const bool xpart = (k0 < HID);
        const int kb = k0 & (HID - 1);
        const float* __restrict__ srcA = xpart ? p.x : p.h;
        #pragma unroll
        for (int i2 = 0; i2 < 8; ++i2) {
            int cidx = t + i2 * 256;
            int row = cidx >> 4;
            int kc = cidx & 15;
            float4 v = *(const float4*)&srcA[(size_t)(bm + row) * HID + kb + kc * 4];
            int idx = row * BK + ((kc * 4) ^ ((row & 7) << 3));
            short4 s;
            s.x = f2bf(v.x); s.y = f2bf(v.y); s.z = f2bf(v.z); s.w = f2bf(v.w);
            *(short4*)&sA[idx] = s;
        }
        #pragma unroll
        for (int i2 = 0; i2 < 16; ++i2) {
            const int g = i2 >> 2;
            int rem = t + (i2 & 3) * 256;
            int row = rem >> 4;
            int kc = rem & 15;
            const float* __restrict__ srcB = xpart ? p.Wx[g] : p.Wh[g];
            float4 v = *(const float4*)&srcB[(size_t)(bn + row) * HID + kb + kc * 4];
            int idx = row * BK + ((kc * 4) ^ ((row & 7) << 3));
            short4 s;
            s.x = f2bf(v.x); s.y = f2bf(v.y); s.z = f2bf(v.z); s.w = f2bf(v.w);
            *(short4*)&sB[g][idx] = s;
        }
        __syncthreads();
        #pragma unroll
        for (int kk = 0; kk < 2; ++kk) {
            bf16x8 a[4];
            #pragma unroll
            for (int m = 0; m < 4; ++m) {
                int row = wm + m * 16 + lr;
                int kidx = (kk * 32 + lk) ^ ((row & 7) << 3);
                a[m] = *(const bf16x8*)&sA[row * BK + kidx];
            }
            #pragma unroll
            for (int g = 0; g < 4; ++g) {
                #pragma unroll
                for (int n = 0; n < 2; ++n) {
                    int brow = wn + n * 16 + lr;
                    int kidx = (kk * 32 + lk) ^ ((brow & 7) << 3);
                    bf16x8 b = *(const bf16x8*)&sB[g][brow * BK + kidx];
                    #pragma unroll
                    for (int m = 0; m < 4; ++m)
                        acc[g][m][n] = __builtin_amdgcn_mfma_f32_16x16x32_bf16(
                            a[m], b, acc[g][m][n], 0, 0, 0);
                }
            }
        }
        __syncthreads();
    }

    float bias[4][2];
    #pragma unroll
    for (int g = 0; g < 4; ++g)
        #pragma unroll
        for (int n = 0; n < 2; ++n)
            bias[g][n] = p.bx[g][bn + wn + n * 16 + lr];

    #pragma unroll
    for (int m = 0; m < 4; ++m) {
        int rbase = bm + wm + m * 16 + (lane >> 4) * 4;
        #pragma unroll
        for (int r = 0; r < 4; ++r) {
            int row = rbase + r;
            #pragma unroll
            for (int n = 0; n < 2; ++n) {
                int col = bn + wn + n * 16 + lr;
                float pf = acc[0][m][n][r] + bias[0][n];
                float pi = acc[1][m][n][r] + bias[1][n];
                float pc = acc[2][m][n][r] + bias[2][n];
                float po = acc[3][m][n][r] + bias[3][n];
                float fg = fmaxf(pf, 0.f);
                float ig = fmaxf(pi, 0.f);
                float og = fmaxf(po, 0.f);
                float ct = fast_tanh(pc);
                float cv = p.c[(size_t)row * HID + col];
                float cn = fg * cv + ig * ct;
                float hn = og * fast_tanh(cn);
                p.oh[(size_t)row * HID + col] = hn;
                p.oc[(size_t)row * HID + col] = cn;
            }
        }
    }
}

extern "C" void kernel_launch(void* const* d_in, const int* in_sizes, int n_in,
                              void* d_out, int out_size, void* d_ws, size_t ws_size,
                              hipStream_t stream) {
    (void)in_sizes; (void)n_in; (void)out_size;
    const size_t A_BYTES = (size_t)BATCH_N * KTOT * 2;
    const size_t B_BYTES = (size_t)4 * HID * KTOT * 2;

    if (ws_size >= A_BYTES + B_BYTES) {
        short* A = (short*)d_ws;
        short* B = A + (size_t)BATCH_N * KTOT;

        CastParams q;
        q.x = (const float*)d_in[0];
        q.h = (const float*)d_in[1];
        for (int g = 0; g < 4; ++g) {
            q.Wx[g] = (const float*)d_in[3 + 3 * g];
            q.Wh[g] = (const float*)d_in[5 + 3 * g];
        }
        q.A = A; q.B = B;
        precast_kernel<<<2048, 256, 0, stream>>>(q);

        GemmParams p;
        p.A = A; p.B = B;
        p.c = (const float*)d_in[2];
        for (int g = 0; g < 4; ++g) p.bx[g] = (const float*)d_in[4 + 3 * g];
        p.oh = (float*)d_out;
        p.oc = (float*)d_out + (size_t)BATCH_N * HID;
        dim3 grid(BATCH_N / 256, HID / 64);   // 16 x 32
        gemm_lstm_8ph<<<grid, 512, 0, stream>>>(p);
    } else {
        Params p;
        p.x = (const float*)d_in[0];
        p.h = (const float*)d_in[1];
        p.c = (const float*)d_in[2];
        for (int g = 0; g < 4; ++g) {
            p.Wx[g] = (const float*)d_in[3 + 3 * g];
            p.bx[g] = (const float*)d_in[4 + 3 * g];
            p.Wh[g] = (const float*)d_in[5 + 3 * g];
        }
        p.oh = (float*)d_out;
        p.oc = (float*)d_out + (size_t)BATCH_N * HID;
        dim3 grid(BATCH_N / 128, HID / 64);
        relulstm_fallback<<<grid, 256, 0, stream>>>(p);
    }
}